// Round 4
// baseline (342.822 us; speedup 1.0000x reference)
//
#include <hip/hip_runtime.h>

typedef unsigned short ushort_t;
typedef __attribute__((ext_vector_type(8))) short short8;   // 8 x bf16 (MFMA A/B frag)
typedef __attribute__((ext_vector_type(4))) float floatx4;  // MFMA C/D frag

// Problem constants (fixed by the reference)
// N=4000 nodes, E=60000 edges, M=16, C=64, H=64, HEADS=8, A=8, VC=8, CE=32, Z=90
// Composite-weight block layout (floats), per role stride RS:
//   WsWa [64*64] @0, WtWa [64*64] @4096, WeWa [32*64] @8192,
//   PsW [64*8] @10240, PtW [64*8] @10752, WeWvWo [32*8] @11264
constexpr int RS = 11520;

__device__ inline float bf2f(ushort_t u) {
    union { unsigned int i; float f; } v; v.i = ((unsigned int)u) << 16; return v.f;
}
__device__ inline ushort_t f2bf(float f) {
    union { float f; unsigned int i; } v; v.f = f;
    unsigned int b = v.i + 0x7FFFu + ((v.i >> 16) & 1u);  // RNE
    return (ushort_t)(b >> 16);
}

// ---------------------------------------------------------------------------
// Kernel A: weight composites.  grid = (6 tasks, 2 roles), 256 thr
// ---------------------------------------------------------------------------
__global__ __launch_bounds__(256) void k_composites(
    const float* __restrict__ Ws0, const float* __restrict__ Wt0, const float* __restrict__ We0,
    const float* __restrict__ Wa0, const float* __restrict__ Wv0, const float* __restrict__ Wo0,
    const float* __restrict__ Ws1, const float* __restrict__ Wt1, const float* __restrict__ We1,
    const float* __restrict__ Wa1, const float* __restrict__ Wv1, const float* __restrict__ Wo1,
    float* __restrict__ cmp)
{
    int task = blockIdx.x;   // 0..5
    int r    = blockIdx.y;   // 0..1
    const float* Ws = r ? Ws1 : Ws0;
    const float* Wt = r ? Wt1 : Wt0;
    const float* We = r ? We1 : We0;
    const float* Wa = r ? Wa1 : Wa0;
    const float* Wv = r ? Wv1 : Wv0;
    const float* Wo = r ? Wo1 : Wo0;
    float* base = cmp + r * RS;

    if (task == 0 || task == 1) {
        const float* L = task ? Wt : Ws;
        float* out = base + task * 4096;
        for (int idx = threadIdx.x; idx < 4096; idx += 256) {
            int c = idx >> 6, j = idx & 63;
            float a = 0.f;
            for (int k = 0; k < 64; ++k) a += L[c * 64 + k] * Wa[k * 64 + j];
            out[idx] = a;
        }
    } else if (task == 2) {
        float* out = base + 8192;
        for (int idx = threadIdx.x; idx < 2048; idx += 256) {
            int ce = idx >> 6, j = idx & 63;
            float a = 0.f;
            for (int k = 0; k < 64; ++k) a += We[ce * 64 + k] * Wa[k * 64 + j];
            out[idx] = a;
        }
    } else {
        // WvWo fold: WvWo[k,h] = sum_vc Wv[k, h*8+vc] * Wo[h*8+vc]
        const float* L = (task == 3) ? Ws : (task == 4) ? Wt : We;
        int rows = (task == 5) ? 32 : 64;
        float* out = base + ((task == 3) ? 10240 : (task == 4) ? 10752 : 11264);
        for (int idx = threadIdx.x; idx < rows * 8; idx += 256) {
            int c = idx >> 3, h = idx & 7;
            float a = 0.f;
            for (int k = 0; k < 64; ++k) {
                float wv = 0.f;
                #pragma unroll
                for (int aa = 0; aa < 8; ++aa) wv += Wv[k * 64 + h * 8 + aa] * Wo[h * 8 + aa];
                a += L[c * 64 + k] * wv;
            }
            out[idx] = a;
        }
    }
}

// ---------------------------------------------------------------------------
// Kernel B: per-node precompute via MFMA, one wave per node (grid-stride).
// Layouts (HW-verified): A[m=lane&15][k=(lane>>4)*8+j],
// B[k=(lane>>4)*8+j][n=lane&15], C/D: col=lane&15, row=(lane>>4)*4+reg.
// ---------------------------------------------------------------------------
__device__ inline short8 bfragW(const float* __restrict__ W, int colBase, int kBase,
                                int q, int n) {
    short8 f;
    #pragma unroll
    for (int j = 0; j < 8; ++j)
        f[j] = (short)f2bf(W[(kBase + q * 8 + j) * 64 + colBase + n]);
    return f;
}
__device__ inline short8 bfragP(const float* __restrict__ P0, const float* __restrict__ P1,
                                int kBase, int q, int n) {
    const float* P = (n < 8) ? P0 : P1;
    int c = n & 7;
    short8 f;
    #pragma unroll
    for (int j = 0; j < 8; ++j)
        f[j] = (short)f2bf(P[(kBase + q * 8 + j) * 8 + c]);
    return f;
}

#define MFMA(a, b, c) __builtin_amdgcn_mfma_f32_16x16x32_bf16((a), (b), (c), 0, 0, 0)

__global__ __launch_bounds__(256, 2) void k_node(
    const float* __restrict__ x, const int* __restrict__ mask,
    const float* __restrict__ cmp,
    float* __restrict__ psrc, float* __restrict__ ptgt,
    ushort_t* __restrict__ srcA, ushort_t* __restrict__ tgtA,
    int N, int totWaves)
{
    int wid  = (int)((blockIdx.x * blockDim.x + threadIdx.x) >> 6);
    int lane = threadIdx.x & 63;
    int q    = lane >> 4;     // quad 0..3
    int n16  = lane & 15;     // 0..15

    short8 Bs0[4][2], Bs1[4][2], Bt0[4][2], Bt1[4][2];
    #pragma unroll
    for (int t = 0; t < 4; ++t) {
        #pragma unroll
        for (int kh = 0; kh < 2; ++kh) {
            Bs0[t][kh] = bfragW(cmp,             t * 16, kh * 32, q, n16);
            Bs1[t][kh] = bfragW(cmp + RS,        t * 16, kh * 32, q, n16);
            Bt0[t][kh] = bfragW(cmp + 4096,      t * 16, kh * 32, q, n16);
            Bt1[t][kh] = bfragW(cmp + RS + 4096, t * 16, kh * 32, q, n16);
        }
    }
    short8 Bp[2], Bq[2];
    #pragma unroll
    for (int kh = 0; kh < 2; ++kh) {
        Bp[kh] = bfragP(cmp + 10240, cmp + RS + 10240, kh * 32, q, n16);
        Bq[kh] = bfragP(cmp + 10752, cmp + RS + 10752, kh * 32, q, n16);
    }

    const floatx4 zero = {0.f, 0.f, 0.f, 0.f};

    for (int nd = wid; nd < N; nd += totWaves) {
        const float* xp = x + (size_t)nd * 1024 + n16 * 64 + q * 8;
        float4 v0 = *(const float4*)(xp);
        float4 v1 = *(const float4*)(xp + 4);
        float4 v2 = *(const float4*)(xp + 32);
        float4 v3 = *(const float4*)(xp + 36);
        short8 a0, a1;
        a0[0] = (short)f2bf(v0.x); a0[1] = (short)f2bf(v0.y);
        a0[2] = (short)f2bf(v0.z); a0[3] = (short)f2bf(v0.w);
        a0[4] = (short)f2bf(v1.x); a0[5] = (short)f2bf(v1.y);
        a0[6] = (short)f2bf(v1.z); a0[7] = (short)f2bf(v1.w);
        a1[0] = (short)f2bf(v2.x); a1[1] = (short)f2bf(v2.y);
        a1[2] = (short)f2bf(v2.z); a1[3] = (short)f2bf(v2.w);
        a1[4] = (short)f2bf(v3.x); a1[5] = (short)f2bf(v3.y);
        a1[6] = (short)f2bf(v3.z); a1[7] = (short)f2bf(v3.w);

        int rsel = (mask[nd] != 0);

        {
            floatx4 c0 = zero, c1 = zero, c2 = zero, c3 = zero;
            c0 = MFMA(a0, Bs0[0][0], c0); c0 = MFMA(a1, Bs0[0][1], c0);
            c1 = MFMA(a0, Bs0[1][0], c1); c1 = MFMA(a1, Bs0[1][1], c1);
            c2 = MFMA(a0, Bs0[2][0], c2); c2 = MFMA(a1, Bs0[2][1], c2);
            c3 = MFMA(a0, Bs0[3][0], c3); c3 = MFMA(a1, Bs0[3][1], c3);
            ushort_t* sp = srcA + (size_t)nd * 2048 + (q * 4) * 64 + n16;
            #pragma unroll
            for (int rr = 0; rr < 4; ++rr) {
                sp[rr * 64 +  0] = f2bf(c0[rr]);
                sp[rr * 64 + 16] = f2bf(c1[rr]);
                sp[rr * 64 + 32] = f2bf(c2[rr]);
                sp[rr * 64 + 48] = f2bf(c3[rr]);
            }
        }
        {
            floatx4 c0 = zero, c1 = zero, c2 = zero, c3 = zero;
            c0 = MFMA(a0, Bs1[0][0], c0); c0 = MFMA(a1, Bs1[0][1], c0);
            c1 = MFMA(a0, Bs1[1][0], c1); c1 = MFMA(a1, Bs1[1][1], c1);
            c2 = MFMA(a0, Bs1[2][0], c2); c2 = MFMA(a1, Bs1[2][1], c2);
            c3 = MFMA(a0, Bs1[3][0], c3); c3 = MFMA(a1, Bs1[3][1], c3);
            ushort_t* sp = srcA + (size_t)nd * 2048 + 1024 + (q * 4) * 64 + n16;
            #pragma unroll
            for (int rr = 0; rr < 4; ++rr) {
                sp[rr * 64 +  0] = f2bf(c0[rr]);
                sp[rr * 64 + 16] = f2bf(c1[rr]);
                sp[rr * 64 + 32] = f2bf(c2[rr]);
                sp[rr * 64 + 48] = f2bf(c3[rr]);
            }
        }
        {
            floatx4 c0 = zero, c1 = zero, c2 = zero, c3 = zero;
            if (rsel) {
                c0 = MFMA(a0, Bt1[0][0], c0); c0 = MFMA(a1, Bt1[0][1], c0);
                c1 = MFMA(a0, Bt1[1][0], c1); c1 = MFMA(a1, Bt1[1][1], c1);
                c2 = MFMA(a0, Bt1[2][0], c2); c2 = MFMA(a1, Bt1[2][1], c2);
                c3 = MFMA(a0, Bt1[3][0], c3); c3 = MFMA(a1, Bt1[3][1], c3);
            } else {
                c0 = MFMA(a0, Bt0[0][0], c0); c0 = MFMA(a1, Bt0[0][1], c0);
                c1 = MFMA(a0, Bt0[1][0], c1); c1 = MFMA(a1, Bt0[1][1], c1);
                c2 = MFMA(a0, Bt0[2][0], c2); c2 = MFMA(a1, Bt0[2][1], c2);
                c3 = MFMA(a0, Bt0[3][0], c3); c3 = MFMA(a1, Bt0[3][1], c3);
            }
            ushort_t* tp = tgtA + (size_t)nd * 1024 + (q * 4) * 64 + n16;
            #pragma unroll
            for (int rr = 0; rr < 4; ++rr) {
                tp[rr * 64 +  0] = f2bf(c0[rr]);
                tp[rr * 64 + 16] = f2bf(c1[rr]);
                tp[rr * 64 + 32] = f2bf(c2[rr]);
                tp[rr * 64 + 48] = f2bf(c3[rr]);
            }
        }
        {
            floatx4 cp = zero;
            cp = MFMA(a0, Bp[0], cp); cp = MFMA(a1, Bp[1], cp);
            if (q == 0) {
                int r = n16 >> 3, h = n16 & 7;
                float* pp = psrc + (size_t)nd * 48 + r * 24 + h;
                pp[0]  = cp[1];
                pp[8]  = cp[2];
                pp[16] = cp[3];
            }
            floatx4 cq = zero;
            cq = MFMA(a0, Bq[0], cq); cq = MFMA(a1, Bq[1], cq);
            if (q == 0 && (n16 >> 3) == rsel) {
                int h = n16 & 7;
                float* pp = ptgt + (size_t)nd * 24 + h;
                pp[0]  = cq[1];
                pp[8]  = cq[2];
                pp[16] = cq[3];
            }
        }
    }
}

// ---------------------------------------------------------------------------
// CSR build: histogram -> block scan -> fill
// ---------------------------------------------------------------------------
__global__ __launch_bounds__(256) void k_hist(
    const int* __restrict__ ei, int* __restrict__ cnt_s, int* __restrict__ cnt_d, int E)
{
    int e = blockIdx.x * 256 + threadIdx.x;
    if (e < E) {
        atomicAdd(&cnt_s[ei[e]], 1);
        atomicAdd(&cnt_d[ei[E + e]], 1);
    }
}

__global__ __launch_bounds__(256) void k_scan(
    const int* __restrict__ cnt_s, const int* __restrict__ cnt_d,
    int* __restrict__ base_s, int* __restrict__ base_d,
    int* __restrict__ woff_s, int* __restrict__ woff_d, int N)
{
    __shared__ int part[256];
    int tid = threadIdx.x;
    int chunk = (N + 255) / 256;
    for (int a = 0; a < 2; ++a) {
        const int* cnt = a ? cnt_d : cnt_s;
        int* base = a ? base_d : base_s;
        int* woff = a ? woff_d : woff_s;
        int lo = tid * chunk, hi = min(lo + chunk, N);
        int sum = 0;
        for (int i = lo; i < hi; ++i) sum += cnt[i];
        part[tid] = sum;
        __syncthreads();
        for (int off = 1; off < 256; off <<= 1) {
            int v = (tid >= off) ? part[tid - off] : 0;
            __syncthreads();
            part[tid] += v;
            __syncthreads();
        }
        int run = tid ? part[tid - 1] : 0;
        for (int i = lo; i < hi; ++i) { base[i] = run; woff[i] = run; run += cnt[i]; }
        __syncthreads();
    }
}

__global__ __launch_bounds__(256) void k_fill(
    const int* __restrict__ ei, int* __restrict__ woff_s, int* __restrict__ woff_d,
    int* __restrict__ csr_s, int* __restrict__ csr_d, int E)
{
    int e = blockIdx.x * 256 + threadIdx.x;
    if (e < E) {
        int p = atomicAdd(&woff_s[ei[e]], 1);      csr_s[p] = e;
        int q = atomicAdd(&woff_d[ei[E + e]], 1);  csr_d[q] = e;
    }
}

// ---------------------------------------------------------------------------
// Kernel C1: src-centric, 4 nodes/block (wave per node), edge loop
// unrolled 4-wide for ILP. Per out-edge: read w0 (64B), write f0s (128B).
// ---------------------------------------------------------------------------
__global__ __launch_bounds__(256) void k_src(
    const int* __restrict__ ei, const int* __restrict__ mask,
    const float* __restrict__ wig, const ushort_t* __restrict__ srcA,
    const int* __restrict__ base_s, const int* __restrict__ cnt_s,
    const int* __restrict__ csr_s, ushort_t* __restrict__ f0s, int E, int N)
{
    int nd = blockIdx.x * 4 + (threadIdx.x >> 6);
    if (nd >= N) return;
    int j = threadIdx.x & 63;
    int num = cnt_s[nd];
    if (num == 0) return;
    int beg = base_s[nd];

    float y0[16], y1[16];
    const ushort_t* sp = srcA + (size_t)nd * 2048 + j;
    #pragma unroll
    for (int n = 0; n < 16; ++n) {
        y0[n] = bf2f(sp[n * 64]);
        y1[n] = bf2f(sp[1024 + n * 64]);
    }

    int i0 = 0;
    for (; i0 + 4 <= num; i0 += 4) {
        int e0 = csr_s[beg + i0], e1 = csr_s[beg + i0 + 1];
        int e2 = csr_s[beg + i0 + 2], e3 = csr_s[beg + i0 + 3];
        int r0 = (mask[ei[E + e0]] != 0), r1 = (mask[ei[E + e1]] != 0);
        int r2 = (mask[ei[E + e2]] != 0), r3 = (mask[ei[E + e3]] != 0);
        const float* w00 = wig + (size_t)e0 * 256;
        const float* w01 = wig + (size_t)e1 * 256;
        const float* w02 = wig + (size_t)e2 * 256;
        const float* w03 = wig + (size_t)e3 * 256;
        float a0 = 0.f, a1 = 0.f, a2 = 0.f, a3 = 0.f;
        #pragma unroll
        for (int n = 0; n < 16; ++n) {
            a0 += w00[n] * (r0 ? y1[n] : y0[n]);
            a1 += w01[n] * (r1 ? y1[n] : y0[n]);
            a2 += w02[n] * (r2 ? y1[n] : y0[n]);
            a3 += w03[n] * (r3 ? y1[n] : y0[n]);
        }
        f0s[(size_t)e0 * 64 + j] = f2bf(a0);
        f0s[(size_t)e1 * 64 + j] = f2bf(a1);
        f0s[(size_t)e2 * 64 + j] = f2bf(a2);
        f0s[(size_t)e3 * 64 + j] = f2bf(a3);
    }
    for (; i0 < num; ++i0) {
        int e = csr_s[beg + i0];
        int rr = (mask[ei[E + e]] != 0);
        const float* w0 = wig + (size_t)e * 256;
        float acc = 0.f;
        #pragma unroll
        for (int n = 0; n < 16; ++n) acc += w0[n] * (rr ? y1[n] : y0[n]);
        f0s[(size_t)e * 64 + j] = f2bf(acc);
    }
}

// ---------------------------------------------------------------------------
// Kernel C2: dst-centric, 4 nodes/block (wave per node), edge loop unrolled
// 4-wide. tgtA + WeWa col + WeWvWo + va in registers; den in registers.
// ---------------------------------------------------------------------------
__global__ __launch_bounds__(256) void k_dst(
    const int* __restrict__ ei, const float* __restrict__ dist,
    const int* __restrict__ zn, const int* __restrict__ mask,
    const float* __restrict__ wig, const float* __restrict__ cmp,
    const float* __restrict__ embs0, const float* __restrict__ embt0, const float* __restrict__ wd0,
    const float* __restrict__ embs1, const float* __restrict__ embt1, const float* __restrict__ wd1,
    const float* __restrict__ va0, const float* __restrict__ va1,
    const ushort_t* __restrict__ tgtA, const ushort_t* __restrict__ f0s,
    const int* __restrict__ base_d, const int* __restrict__ cnt_d,
    const int* __restrict__ csr_d,
    float* __restrict__ den, float* __restrict__ exb, float* __restrict__ ejb, int E, int N)
{
    int nd = blockIdx.x * 4 + (threadIdx.x >> 6);
    if (nd >= N) return;
    int j = threadIdx.x & 63;
    int num = cnt_d[nd];
    if (num == 0) { if (j < 8) den[nd * 8 + j] = 0.f; return; }
    int beg = base_d[nd];
    int r = (mask[nd] != 0);

    const float* embs = r ? embs1 : embs0;
    const float* embt = r ? embt1 : embt0;
    const float* wd   = r ? wd1   : wd0;
    float vav = r ? va1[j] : va0[j];

    float y[16];
    const ushort_t* tp = tgtA + (size_t)nd * 1024 + j;
    #pragma unroll
    for (int n = 0; n < 16; ++n) y[n] = bf2f(tp[n * 64]);

    const float* WeWa   = cmp + r * RS + 8192;
    const float* WeWvWo = cmp + r * RS + 11264;
    int h8 = j & 7, ce = j & 31;
    float wa[32], wvo[32];
    #pragma unroll
    for (int c = 0; c < 32; ++c) wa[c]  = WeWa[c * 64 + j];
    #pragma unroll
    for (int c = 0; c < 32; ++c) wvo[c] = WeWvWo[c * 8 + h8];

    int zt = zn[nd];
    float wdv = wd[ce];
    float embtv = embt[zt * 32 + ce];

    float den_acc = 0.f;

    int i0 = 0;
    for (; i0 + 4 <= num; i0 += 4) {
        int e0 = csr_d[beg + i0],     e1 = csr_d[beg + i0 + 1];
        int e2 = csr_d[beg + i0 + 2], e3 = csr_d[beg + i0 + 3];
        int s0 = ei[e0], s1 = ei[e1], s2 = ei[e2], s3 = ei[e3];
        float d0 = dist[e0], d1 = dist[e1], d2 = dist[e2], d3 = dist[e3];

        float z0 = d0 * wdv + embs[zn[s0] * 32 + ce] + embtv;
        float z1 = d1 * wdv + embs[zn[s1] * 32 + ce] + embtv;
        float z2 = d2 * wdv + embs[zn[s2] * 32 + ce] + embtv;
        float z3 = d3 * wdv + embs[zn[s3] * 32 + ce] + embtv;
        float es0 = z0 / (1.f + __expf(-z0));
        float es1 = z1 / (1.f + __expf(-z1));
        float es2 = z2 / (1.f + __expf(-z2));
        float es3 = z3 / (1.f + __expf(-z3));

        const float* w00 = wig + (size_t)e0 * 256;
        const float* w01 = wig + (size_t)e1 * 256;
        const float* w02 = wig + (size_t)e2 * 256;
        const float* w03 = wig + (size_t)e3 * 256;
        float f0 = 0.f, f1 = 0.f, f2 = 0.f, f3 = 0.f;
        #pragma unroll
        for (int n = 0; n < 16; ++n) {
            f0 += w00[n] * y[n];
            f1 += w01[n] * y[n];
            f2 += w02[n] * y[n];
            f3 += w03[n] * y[n];
        }
        float ej0 = 0.f, ej1 = 0.f, ej2 = 0.f, ej3 = 0.f;
        #pragma unroll
        for (int c = 0; c < 32; ++c) {
            float v0 = __shfl(es0, c, 64);
            float v1 = __shfl(es1, c, 64);
            float v2 = __shfl(es2, c, 64);
            float v3 = __shfl(es3, c, 64);
            f0 += v0 * wa[c]; ej0 += v0 * wvo[c];
            f1 += v1 * wa[c]; ej1 += v1 * wvo[c];
            f2 += v2 * wa[c]; ej2 += v2 * wvo[c];
            f3 += v3 * wa[c]; ej3 += v3 * wvo[c];
        }
        f0 += bf2f(f0s[(size_t)e0 * 64 + j]);
        f1 += bf2f(f0s[(size_t)e1 * 64 + j]);
        f2 += bf2f(f0s[(size_t)e2 * 64 + j]);
        f3 += bf2f(f0s[(size_t)e3 * 64 + j]);

        float l0 = (f0 > 0.f ? f0 : 0.2f * f0) * vav;
        float l1 = (f1 > 0.f ? f1 : 0.2f * f1) * vav;
        float l2 = (f2 > 0.f ? f2 : 0.2f * f2) * vav;
        float l3 = (f3 > 0.f ? f3 : 0.2f * f3) * vav;
        #pragma unroll
        for (int off = 1; off < 8; off <<= 1) {
            l0 += __shfl_xor(l0, off);
            l1 += __shfl_xor(l1, off);
            l2 += __shfl_xor(l2, off);
            l3 += __shfl_xor(l3, off);
        }
        float x0 = __expf(l0), x1 = __expf(l1), x2 = __expf(l2), x3 = __expf(l3);
        int sl = (j & 7) * 8;
        float xh0 = __shfl(x0, sl), xh1 = __shfl(x1, sl);
        float xh2 = __shfl(x2, sl), xh3 = __shfl(x3, sl);
        den_acc += (xh0 + xh1) + (xh2 + xh3);
        if (j < 8) {
            exb[(size_t)e0 * 8 + j] = xh0;  ejb[(size_t)e0 * 8 + j] = ej0;
            exb[(size_t)e1 * 8 + j] = xh1;  ejb[(size_t)e1 * 8 + j] = ej1;
            exb[(size_t)e2 * 8 + j] = xh2;  ejb[(size_t)e2 * 8 + j] = ej2;
            exb[(size_t)e3 * 8 + j] = xh3;  ejb[(size_t)e3 * 8 + j] = ej3;
        }
    }
    for (; i0 < num; ++i0) {
        int e = csr_d[beg + i0];
        int src = ei[e];
        float d = dist[e];
        float z = d * wdv + embs[zn[src] * 32 + ce] + embtv;
        float es = z / (1.f + __expf(-z));
        float f0a = 0.f, ej = 0.f;
        #pragma unroll
        for (int c = 0; c < 32; ++c) {
            float ev = __shfl(es, c, 64);
            f0a += ev * wa[c];
            ej  += ev * wvo[c];
        }
        const float* w0 = wig + (size_t)e * 256;
        #pragma unroll
        for (int n = 0; n < 16; ++n) f0a += w0[n] * y[n];
        f0a += bf2f(f0s[(size_t)e * 64 + j]);
        float la = (f0a > 0.f ? f0a : 0.2f * f0a) * vav;
        #pragma unroll
        for (int off = 1; off < 8; off <<= 1) la += __shfl_xor(la, off);
        float ex = __expf(la);
        float exh = __shfl(ex, (j & 7) * 8);
        den_acc += exh;
        if (j < 8) {
            exb[(size_t)e * 8 + j] = exh;
            ejb[(size_t)e * 8 + j] = ej;
        }
    }
    if (j < 8) den[nd * 8 + j] = den_acc;
}

// ---------------------------------------------------------------------------
// Kernel D: dst-centric output, 4 nodes/block (wave per node), unrolled 4.
// lanes t<24: c=t>>3 (output row), h=t&7 (head). Single write, no atomics.
// ---------------------------------------------------------------------------
__global__ __launch_bounds__(256) void k_out(
    const int* __restrict__ ei, const int* __restrict__ mask,
    const float* __restrict__ wig,
    const float* __restrict__ psrc, const float* __restrict__ ptgt,
    const float* __restrict__ exb, const float* __restrict__ ejb,
    const float* __restrict__ den,
    const int* __restrict__ base_d, const int* __restrict__ cnt_d,
    const int* __restrict__ csr_d,
    float* __restrict__ out, int E, int N)
{
    int nd = blockIdx.x * 4 + (threadIdx.x >> 6);
    if (nd >= N) return;
    int t = threadIdx.x & 63;
    int c = t >> 3, h = t & 7;
    int num = cnt_d[nd];
    int beg = base_d[nd];
    int r = (mask[nd] != 0);
    bool act = (t < 24);

    float acc = 0.f;
    float ptv = act ? ptgt[(size_t)nd * 24 + t] : 0.f;
    float dv  = act ? (den[nd * 8 + h] + 1e-9f) : 1.f;
    float inv = 1.f / dv;

    int i0 = 0;
    for (; i0 + 4 <= num; i0 += 4) {
        int e0 = csr_d[beg + i0],     e1 = csr_d[beg + i0 + 1];
        int e2 = csr_d[beg + i0 + 2], e3 = csr_d[beg + i0 + 3];
        int s0 = ei[e0], s1 = ei[e1], s2 = ei[e2], s3 = ei[e3];
        float al0 = 0.f, al1 = 0.f, al2 = 0.f, al3 = 0.f;
        float ejv0 = 0.f, ejv1 = 0.f, ejv2 = 0.f, ejv3 = 0.f;
        float ps0 = 0.f, ps1 = 0.f, ps2 = 0.f, ps3 = 0.f;
        if (act) {
            al0 = exb[(size_t)e0 * 8 + h] * inv;  ejv0 = ejb[(size_t)e0 * 8 + h];
            al1 = exb[(size_t)e1 * 8 + h] * inv;  ejv1 = ejb[(size_t)e1 * 8 + h];
            al2 = exb[(size_t)e2 * 8 + h] * inv;  ejv2 = ejb[(size_t)e2 * 8 + h];
            al3 = exb[(size_t)e3 * 8 + h] * inv;  ejv3 = ejb[(size_t)e3 * 8 + h];
            ps0 = psrc[(size_t)s0 * 48 + r * 24 + t];
            ps1 = psrc[(size_t)s1 * 48 + r * 24 + t];
            ps2 = psrc[(size_t)s2 * 48 + r * 24 + t];
            ps3 = psrc[(size_t)s3 * 48 + r * 24 + t];
        }
        float w0 = wig[(size_t)e0 * 256 + 1 + c];
        float w1 = wig[(size_t)e1 * 256 + 1 + c];
        float w2 = wig[(size_t)e2 * 256 + 1 + c];
        float w3 = wig[(size_t)e3 * 256 + 1 + c];
        acc += al0 * (ps0 + ptv) + w0 * (al0 * ejv0);
        acc += al1 * (ps1 + ptv) + w1 * (al1 * ejv1);
        acc += al2 * (ps2 + ptv) + w2 * (al2 * ejv2);
        acc += al3 * (ps3 + ptv) + w3 * (al3 * ejv3);
    }
    for (; i0 < num; ++i0) {
        int e = csr_d[beg + i0];
        int src = ei[e];
        float ex  = act ? exb[(size_t)e * 8 + h] : 0.f;
        float ejv = act ? ejb[(size_t)e * 8 + h] : 0.f;
        float psv = act ? psrc[(size_t)src * 48 + r * 24 + t] : 0.f;
        float al = ex * inv;
        float w0c = wig[(size_t)e * 256 + 1 + c];
        acc += al * (psv + ptv) + w0c * (al * ejv);
    }
    acc += __shfl_xor(acc, 1);
    acc += __shfl_xor(acc, 2);
    acc += __shfl_xor(acc, 4);
    if (act && h == 0) out[nd * 3 + c] = acc;
}

// ---------------------------------------------------------------------------
extern "C" void kernel_launch(void* const* d_in, const int* in_sizes, int n_in,
                              void* d_out, int out_size, void* d_ws, size_t ws_size,
                              hipStream_t stream) {
    const float* x    = (const float*)d_in[0];
    const int*   zn   = (const int*)d_in[1];
    const float* dist = (const float*)d_in[2];
    const int*   ei   = (const int*)d_in[3];
    const int*   mask = (const int*)d_in[4];
    const float* wig  = (const float*)d_in[5];
    // per role: emb_s, emb_t, w_d, We, Ws, Wt, Wa, va, Wv, Wo
    const float* fs[10]; const float* dn[10];
    for (int i = 0; i < 10; ++i) { fs[i] = (const float*)d_in[6 + i]; dn[i] = (const float*)d_in[16 + i]; }

    int N = in_sizes[1];   // atomic_numbers count
    int E = in_sizes[2];   // edge_distance count

    // workspace carve-up
    float* cmp  = (float*)d_ws;                    // 2*RS
    float* den  = cmp + 2 * RS;                    // N*8
    float* exb  = den + (size_t)N * 8;             // E*8
    float* ejb  = exb + (size_t)E * 8;             // E*8
    float* psrc = ejb + (size_t)E * 8;             // N*48
    float* ptgt = psrc + (size_t)N * 48;           // N*24
    int* cnt_s  = (int*)(ptgt + (size_t)N * 24);   // N
    int* cnt_d  = cnt_s + N;                       // N
    int* base_s = cnt_d + N;                       // N
    int* base_d = base_s + N;                      // N
    int* woff_s = base_d + N;                      // N
    int* woff_d = woff_s + N;                      // N
    int* csr_s  = woff_d + N;                      // E
    int* csr_d  = csr_s + E;                       // E
    size_t off = (size_t)((char*)(csr_d + E) - (char*)d_ws);
    off = (off + 15) & ~(size_t)15;
    ushort_t* srcA = (ushort_t*)((char*)d_ws + off);      // N*2048 bf16
    ushort_t* tgtA = srcA + (size_t)N * 2048;             // N*1024 bf16
    ushort_t* f0s  = tgtA + (size_t)N * 1024;             // E*64 bf16

    hipMemsetAsync(cnt_s, 0, (size_t)2 * N * sizeof(int), stream);

    k_composites<<<dim3(6, 2), 256, 0, stream>>>(
        fs[4], fs[5], fs[3], fs[6], fs[8], fs[9],
        dn[4], dn[5], dn[3], dn[6], dn[8], dn[9], cmp);

    int nodeBlocks = 512;
    int totWaves = nodeBlocks * (256 / 64);
    k_node<<<nodeBlocks, 256, 0, stream>>>(x, mask, cmp, psrc, ptgt, srcA, tgtA, N, totWaves);

    k_hist<<<(E + 255) / 256, 256, 0, stream>>>(ei, cnt_s, cnt_d, E);
    k_scan<<<1, 256, 0, stream>>>(cnt_s, cnt_d, base_s, base_d, woff_s, woff_d, N);
    k_fill<<<(E + 255) / 256, 256, 0, stream>>>(ei, woff_s, woff_d, csr_s, csr_d, E);

    int nb4 = (N + 3) / 4;
    k_src<<<nb4, 256, 0, stream>>>(ei, mask, wig, srcA, base_s, cnt_s, csr_s, f0s, E, N);

    k_dst<<<nb4, 256, 0, stream>>>(
        ei, dist, zn, mask, wig, cmp,
        fs[0], fs[1], fs[2], dn[0], dn[1], dn[2],
        fs[7], dn[7], tgtA, f0s, base_d, cnt_d, csr_d, den, exb, ejb, E, N);

    k_out<<<nb4, 256, 0, stream>>>(
        ei, mask, wig, psrc, ptgt, exb, ejb, den, base_d, cnt_d, csr_d,
        (float*)d_out, E, N);
}

// Round 5
// 321.261 us; speedup vs baseline: 1.0671x; 1.0671x over previous
//
#include <hip/hip_runtime.h>

typedef unsigned short ushort_t;
typedef __attribute__((ext_vector_type(8))) short short8;   // 8 x bf16 (MFMA A/B frag)
typedef __attribute__((ext_vector_type(4))) float floatx4;  // MFMA C/D frag

// Problem constants (fixed by the reference)
// N=4000 nodes, E=60000 edges, M=16, C=64, H=64, HEADS=8, A=8, VC=8, CE=32, Z=90
// Composite-weight block layout (floats), per role stride RS:
//   WsWa [64*64] @0, WtWa [64*64] @4096, WeWa [32*64] @8192,
//   PsW [64*8] @10240, PtW [64*8] @10752, WeWvWo [32*8] @11264
constexpr int RS = 11520;

__device__ inline float bf2f(ushort_t u) {
    union { unsigned int i; float f; } v; v.i = ((unsigned int)u) << 16; return v.f;
}
__device__ inline ushort_t f2bf(float f) {
    union { float f; unsigned int i; } v; v.f = f;
    unsigned int b = v.i + 0x7FFFu + ((v.i >> 16) & 1u);  // RNE
    return (ushort_t)(b >> 16);
}

// ---------------------------------------------------------------------------
// Kernel A: weight composites.  grid = (6 tasks, 2 roles), 256 thr
// ---------------------------------------------------------------------------
__global__ __launch_bounds__(256) void k_composites(
    const float* __restrict__ Ws0, const float* __restrict__ Wt0, const float* __restrict__ We0,
    const float* __restrict__ Wa0, const float* __restrict__ Wv0, const float* __restrict__ Wo0,
    const float* __restrict__ Ws1, const float* __restrict__ Wt1, const float* __restrict__ We1,
    const float* __restrict__ Wa1, const float* __restrict__ Wv1, const float* __restrict__ Wo1,
    float* __restrict__ cmp)
{
    int task = blockIdx.x;   // 0..5
    int r    = blockIdx.y;   // 0..1
    const float* Ws = r ? Ws1 : Ws0;
    const float* Wt = r ? Wt1 : Wt0;
    const float* We = r ? We1 : We0;
    const float* Wa = r ? Wa1 : Wa0;
    const float* Wv = r ? Wv1 : Wv0;
    const float* Wo = r ? Wo1 : Wo0;
    float* base = cmp + r * RS;

    if (task == 0 || task == 1) {
        const float* L = task ? Wt : Ws;
        float* out = base + task * 4096;
        for (int idx = threadIdx.x; idx < 4096; idx += 256) {
            int c = idx >> 6, j = idx & 63;
            float a = 0.f;
            for (int k = 0; k < 64; ++k) a += L[c * 64 + k] * Wa[k * 64 + j];
            out[idx] = a;
        }
    } else if (task == 2) {
        float* out = base + 8192;
        for (int idx = threadIdx.x; idx < 2048; idx += 256) {
            int ce = idx >> 6, j = idx & 63;
            float a = 0.f;
            for (int k = 0; k < 64; ++k) a += We[ce * 64 + k] * Wa[k * 64 + j];
            out[idx] = a;
        }
    } else {
        // WvWo fold: WvWo[k,h] = sum_vc Wv[k, h*8+vc] * Wo[h*8+vc]
        const float* L = (task == 3) ? Ws : (task == 4) ? Wt : We;
        int rows = (task == 5) ? 32 : 64;
        float* out = base + ((task == 3) ? 10240 : (task == 4) ? 10752 : 11264);
        for (int idx = threadIdx.x; idx < rows * 8; idx += 256) {
            int c = idx >> 3, h = idx & 7;
            float a = 0.f;
            for (int k = 0; k < 64; ++k) {
                float wv = 0.f;
                #pragma unroll
                for (int aa = 0; aa < 8; ++aa) wv += Wv[k * 64 + h * 8 + aa] * Wo[h * 8 + aa];
                a += L[c * 64 + k] * wv;
            }
            out[idx] = a;
        }
    }
}

// ---------------------------------------------------------------------------
// Kernel B: per-node precompute via MFMA, one wave per node (grid-stride).
// Layouts (HW-verified): A[m=lane&15][k=(lane>>4)*8+j],
// B[k=(lane>>4)*8+j][n=lane&15], C/D: col=lane&15, row=(lane>>4)*4+reg.
// ---------------------------------------------------------------------------
__device__ inline short8 bfragW(const float* __restrict__ W, int colBase, int kBase,
                                int q, int n) {
    short8 f;
    #pragma unroll
    for (int j = 0; j < 8; ++j)
        f[j] = (short)f2bf(W[(kBase + q * 8 + j) * 64 + colBase + n]);
    return f;
}
__device__ inline short8 bfragP(const float* __restrict__ P0, const float* __restrict__ P1,
                                int kBase, int q, int n) {
    const float* P = (n < 8) ? P0 : P1;
    int c = n & 7;
    short8 f;
    #pragma unroll
    for (int j = 0; j < 8; ++j)
        f[j] = (short)f2bf(P[(kBase + q * 8 + j) * 8 + c]);
    return f;
}

#define MFMA(a, b, c) __builtin_amdgcn_mfma_f32_16x16x32_bf16((a), (b), (c), 0, 0, 0)

__global__ __launch_bounds__(256, 2) void k_node(
    const float* __restrict__ x, const int* __restrict__ mask,
    const float* __restrict__ cmp,
    float* __restrict__ psrc, float* __restrict__ ptgt,
    ushort_t* __restrict__ srcA, ushort_t* __restrict__ tgtA,
    int N, int totWaves)
{
    int wid  = (int)((blockIdx.x * blockDim.x + threadIdx.x) >> 6);
    int lane = threadIdx.x & 63;
    int q    = lane >> 4;     // quad 0..3
    int n16  = lane & 15;     // 0..15

    short8 Bs0[4][2], Bs1[4][2], Bt0[4][2], Bt1[4][2];
    #pragma unroll
    for (int t = 0; t < 4; ++t) {
        #pragma unroll
        for (int kh = 0; kh < 2; ++kh) {
            Bs0[t][kh] = bfragW(cmp,             t * 16, kh * 32, q, n16);
            Bs1[t][kh] = bfragW(cmp + RS,        t * 16, kh * 32, q, n16);
            Bt0[t][kh] = bfragW(cmp + 4096,      t * 16, kh * 32, q, n16);
            Bt1[t][kh] = bfragW(cmp + RS + 4096, t * 16, kh * 32, q, n16);
        }
    }
    short8 Bp[2], Bq[2];
    #pragma unroll
    for (int kh = 0; kh < 2; ++kh) {
        Bp[kh] = bfragP(cmp + 10240, cmp + RS + 10240, kh * 32, q, n16);
        Bq[kh] = bfragP(cmp + 10752, cmp + RS + 10752, kh * 32, q, n16);
    }

    const floatx4 zero = {0.f, 0.f, 0.f, 0.f};

    for (int nd = wid; nd < N; nd += totWaves) {
        const float* xp = x + (size_t)nd * 1024 + n16 * 64 + q * 8;
        float4 v0 = *(const float4*)(xp);
        float4 v1 = *(const float4*)(xp + 4);
        float4 v2 = *(const float4*)(xp + 32);
        float4 v3 = *(const float4*)(xp + 36);
        short8 a0, a1;
        a0[0] = (short)f2bf(v0.x); a0[1] = (short)f2bf(v0.y);
        a0[2] = (short)f2bf(v0.z); a0[3] = (short)f2bf(v0.w);
        a0[4] = (short)f2bf(v1.x); a0[5] = (short)f2bf(v1.y);
        a0[6] = (short)f2bf(v1.z); a0[7] = (short)f2bf(v1.w);
        a1[0] = (short)f2bf(v2.x); a1[1] = (short)f2bf(v2.y);
        a1[2] = (short)f2bf(v2.z); a1[3] = (short)f2bf(v2.w);
        a1[4] = (short)f2bf(v3.x); a1[5] = (short)f2bf(v3.y);
        a1[6] = (short)f2bf(v3.z); a1[7] = (short)f2bf(v3.w);

        int rsel = (mask[nd] != 0);

        {
            floatx4 c0 = zero, c1 = zero, c2 = zero, c3 = zero;
            c0 = MFMA(a0, Bs0[0][0], c0); c0 = MFMA(a1, Bs0[0][1], c0);
            c1 = MFMA(a0, Bs0[1][0], c1); c1 = MFMA(a1, Bs0[1][1], c1);
            c2 = MFMA(a0, Bs0[2][0], c2); c2 = MFMA(a1, Bs0[2][1], c2);
            c3 = MFMA(a0, Bs0[3][0], c3); c3 = MFMA(a1, Bs0[3][1], c3);
            ushort_t* sp = srcA + (size_t)nd * 2048 + (q * 4) * 64 + n16;
            #pragma unroll
            for (int rr = 0; rr < 4; ++rr) {
                sp[rr * 64 +  0] = f2bf(c0[rr]);
                sp[rr * 64 + 16] = f2bf(c1[rr]);
                sp[rr * 64 + 32] = f2bf(c2[rr]);
                sp[rr * 64 + 48] = f2bf(c3[rr]);
            }
        }
        {
            floatx4 c0 = zero, c1 = zero, c2 = zero, c3 = zero;
            c0 = MFMA(a0, Bs1[0][0], c0); c0 = MFMA(a1, Bs1[0][1], c0);
            c1 = MFMA(a0, Bs1[1][0], c1); c1 = MFMA(a1, Bs1[1][1], c1);
            c2 = MFMA(a0, Bs1[2][0], c2); c2 = MFMA(a1, Bs1[2][1], c2);
            c3 = MFMA(a0, Bs1[3][0], c3); c3 = MFMA(a1, Bs1[3][1], c3);
            ushort_t* sp = srcA + (size_t)nd * 2048 + 1024 + (q * 4) * 64 + n16;
            #pragma unroll
            for (int rr = 0; rr < 4; ++rr) {
                sp[rr * 64 +  0] = f2bf(c0[rr]);
                sp[rr * 64 + 16] = f2bf(c1[rr]);
                sp[rr * 64 + 32] = f2bf(c2[rr]);
                sp[rr * 64 + 48] = f2bf(c3[rr]);
            }
        }
        {
            floatx4 c0 = zero, c1 = zero, c2 = zero, c3 = zero;
            if (rsel) {
                c0 = MFMA(a0, Bt1[0][0], c0); c0 = MFMA(a1, Bt1[0][1], c0);
                c1 = MFMA(a0, Bt1[1][0], c1); c1 = MFMA(a1, Bt1[1][1], c1);
                c2 = MFMA(a0, Bt1[2][0], c2); c2 = MFMA(a1, Bt1[2][1], c2);
                c3 = MFMA(a0, Bt1[3][0], c3); c3 = MFMA(a1, Bt1[3][1], c3);
            } else {
                c0 = MFMA(a0, Bt0[0][0], c0); c0 = MFMA(a1, Bt0[0][1], c0);
                c1 = MFMA(a0, Bt0[1][0], c1); c1 = MFMA(a1, Bt0[1][1], c1);
                c2 = MFMA(a0, Bt0[2][0], c2); c2 = MFMA(a1, Bt0[2][1], c2);
                c3 = MFMA(a0, Bt0[3][0], c3); c3 = MFMA(a1, Bt0[3][1], c3);
            }
            ushort_t* tp = tgtA + (size_t)nd * 1024 + (q * 4) * 64 + n16;
            #pragma unroll
            for (int rr = 0; rr < 4; ++rr) {
                tp[rr * 64 +  0] = f2bf(c0[rr]);
                tp[rr * 64 + 16] = f2bf(c1[rr]);
                tp[rr * 64 + 32] = f2bf(c2[rr]);
                tp[rr * 64 + 48] = f2bf(c3[rr]);
            }
        }
        {
            floatx4 cp = zero;
            cp = MFMA(a0, Bp[0], cp); cp = MFMA(a1, Bp[1], cp);
            if (q == 0) {
                int r = n16 >> 3, h = n16 & 7;
                float* pp = psrc + (size_t)nd * 48 + r * 24 + h;
                pp[0]  = cp[1];
                pp[8]  = cp[2];
                pp[16] = cp[3];
            }
            floatx4 cq = zero;
            cq = MFMA(a0, Bq[0], cq); cq = MFMA(a1, Bq[1], cq);
            if (q == 0 && (n16 >> 3) == rsel) {
                int h = n16 & 7;
                float* pp = ptgt + (size_t)nd * 24 + h;
                pp[0]  = cq[1];
                pp[8]  = cq[2];
                pp[16] = cq[3];
            }
        }
    }
}

// ---------------------------------------------------------------------------
// CSR build: histogram -> block scan -> fill (+aux per-position streams)
// ---------------------------------------------------------------------------
__global__ __launch_bounds__(256) void k_hist(
    const int* __restrict__ ei, int* __restrict__ cnt_s, int* __restrict__ cnt_d, int E)
{
    int e = blockIdx.x * 256 + threadIdx.x;
    if (e < E) {
        atomicAdd(&cnt_s[ei[e]], 1);
        atomicAdd(&cnt_d[ei[E + e]], 1);
    }
}

__global__ __launch_bounds__(256) void k_scan(
    const int* __restrict__ cnt_s, const int* __restrict__ cnt_d,
    int* __restrict__ base_s, int* __restrict__ base_d,
    int* __restrict__ woff_s, int* __restrict__ woff_d, int N)
{
    __shared__ int part[256];
    int tid = threadIdx.x;
    int chunk = (N + 255) / 256;
    for (int a = 0; a < 2; ++a) {
        const int* cnt = a ? cnt_d : cnt_s;
        int* base = a ? base_d : base_s;
        int* woff = a ? woff_d : woff_s;
        int lo = tid * chunk, hi = min(lo + chunk, N);
        int sum = 0;
        for (int i = lo; i < hi; ++i) sum += cnt[i];
        part[tid] = sum;
        __syncthreads();
        for (int off = 1; off < 256; off <<= 1) {
            int v = (tid >= off) ? part[tid - off] : 0;
            __syncthreads();
            part[tid] += v;
            __syncthreads();
        }
        int run = tid ? part[tid - 1] : 0;
        for (int i = lo; i < hi; ++i) { base[i] = run; woff[i] = run; run += cnt[i]; }
        __syncthreads();
    }
}

__global__ __launch_bounds__(256) void k_fill(
    const int* __restrict__ ei, int* __restrict__ woff_s, int* __restrict__ woff_d,
    int* __restrict__ cs_e, int* __restrict__ cs_src, int* __restrict__ cs_dst,
    int* __restrict__ cd_e, int* __restrict__ cd_src, int* __restrict__ cd_dst,
    int* __restrict__ pos_d, int E)
{
    int e = blockIdx.x * 256 + threadIdx.x;
    if (e < E) {
        int s = ei[e], t = ei[E + e];
        int p = atomicAdd(&woff_s[s], 1);
        cs_e[p] = e; cs_src[p] = s; cs_dst[p] = t;
        int q = atomicAdd(&woff_d[t], 1);
        cd_e[q] = e; cd_src[q] = s; cd_dst[q] = t;
        pos_d[e] = q;
    }
}

// ---------------------------------------------------------------------------
// Kernel C1: edge-centric src dot, iterated in csr_s (src-sorted) order for
// srcA L1 locality. Wave per edge (lane=j), 4 edges/wave, 16 edges/block.
// Writes f0s at the edge's DST-sorted position (pos_d) so downstream reads
// are sequential.
// ---------------------------------------------------------------------------
__global__ __launch_bounds__(256) void k_srcE(
    const int* __restrict__ cs_e, const int* __restrict__ cs_src,
    const int* __restrict__ cs_dst, const int* __restrict__ mask,
    const int* __restrict__ pos_d, const float* __restrict__ wig,
    const ushort_t* __restrict__ srcA, ushort_t* __restrict__ f0s, int E)
{
    int wv = threadIdx.x >> 6, j = threadIdx.x & 63;
    int ibase = blockIdx.x * 16 + wv * 4;
    for (int k = 0; k < 4; ++k) {
        int p = ibase + k;
        if (p >= E) break;
        int e = cs_e[p], src = cs_src[p], dst = cs_dst[p];
        int r = (mask[dst] != 0);
        int qd = pos_d[e];
        const ushort_t* sp = srcA + (size_t)src * 2048 + r * 1024 + j;
        const float* w0 = wig + (size_t)e * 256;
        float acc = 0.f;
        #pragma unroll
        for (int n = 0; n < 16; ++n) acc += w0[n] * bf2f(sp[n * 64]);
        f0s[(size_t)qd * 64 + j] = f2bf(acc);
    }
}

// ---------------------------------------------------------------------------
// Kernel C2: edge-centric logits, iterated in csr_d (dst-sorted) order for
// tgtA L1 locality. Wave per edge, 4 edges/wave, 16 edges/block.
// f0s/exb/ejb are pos-indexed (sequential). den via atomics (localized).
// ---------------------------------------------------------------------------
__global__ __launch_bounds__(256) void k_edge(
    const int* __restrict__ cd_e, const int* __restrict__ cd_src,
    const int* __restrict__ cd_dst,
    const float* __restrict__ dist, const int* __restrict__ zn,
    const int* __restrict__ mask,
    const float* __restrict__ wig, const float* __restrict__ cmp,
    const float* __restrict__ embs0, const float* __restrict__ embt0, const float* __restrict__ wd0,
    const float* __restrict__ embs1, const float* __restrict__ embt1, const float* __restrict__ wd1,
    const float* __restrict__ va0, const float* __restrict__ va1,
    const ushort_t* __restrict__ tgtA, const ushort_t* __restrict__ f0s,
    float* __restrict__ den, float* __restrict__ exb, float* __restrict__ ejb, int E)
{
    int wv = threadIdx.x >> 6, j = threadIdx.x & 63;
    int ibase = blockIdx.x * 16 + wv * 4;
    int ce = j & 31, h8 = j & 7;
    for (int k = 0; k < 4; ++k) {
        int p = ibase + k;
        if (p >= E) break;
        int e = cd_e[p], src = cd_src[p], dst = cd_dst[p];
        int r = (mask[dst] != 0);
        float d = dist[e];

        float z = r ? (d * wd1[ce] + embs1[zn[src] * 32 + ce] + embt1[zn[dst] * 32 + ce])
                    : (d * wd0[ce] + embs0[zn[src] * 32 + ce] + embt0[zn[dst] * 32 + ce]);
        float es = z / (1.f + __expf(-z));   // silu

        const float* WeWa   = cmp + r * RS + 8192;
        const float* WeWvWo = cmp + r * RS + 11264;
        float f0a = bf2f(f0s[(size_t)p * 64 + j]);
        float ej = 0.f;
        #pragma unroll
        for (int c = 0; c < 32; ++c) {
            float ev = __shfl(es, c, 64);
            f0a += ev * WeWa[c * 64 + j];
            ej  += ev * WeWvWo[c * 8 + h8];
        }

        const ushort_t* tp = tgtA + (size_t)dst * 1024 + j;
        const float* w0 = wig + (size_t)e * 256;
        #pragma unroll
        for (int n = 0; n < 16; ++n) f0a += w0[n] * bf2f(tp[n * 64]);

        float la = f0a > 0.f ? f0a : 0.2f * f0a;   // leaky_relu(0.2)
        float val = la * (r ? va1[j] : va0[j]);
        val += __shfl_xor(val, 1);
        val += __shfl_xor(val, 2);
        val += __shfl_xor(val, 4);                  // logit per 8-lane head group
        float ex = __expf(val);                     // no-max softmax (logits bounded)
        if (h8 == 0) {
            atomicAdd(&den[dst * 8 + (j >> 3)], ex);
            exb[(size_t)p * 8 + (j >> 3)] = ex;
        }
        if (j < 8) ejb[(size_t)p * 8 + j] = ej;
    }
}

// ---------------------------------------------------------------------------
// Kernel D: dst-centric output (no atomics). Wave per node, 4 nodes/block.
// exb/ejb/cd_* reads are sequential per node; psrc is an L2-resident table.
// ---------------------------------------------------------------------------
__global__ __launch_bounds__(256) void k_out(
    const int* __restrict__ cd_e, const int* __restrict__ cd_src,
    const int* __restrict__ mask, const float* __restrict__ wig,
    const float* __restrict__ psrc, const float* __restrict__ ptgt,
    const float* __restrict__ exb, const float* __restrict__ ejb,
    const float* __restrict__ den,
    const int* __restrict__ base_d, const int* __restrict__ cnt_d,
    float* __restrict__ out, int N)
{
    int nd = blockIdx.x * 4 + (threadIdx.x >> 6);
    if (nd >= N) return;
    int t = threadIdx.x & 63;
    int c = t >> 3, h = t & 7;
    int num = cnt_d[nd];
    int beg = base_d[nd];
    int r = (mask[nd] != 0);
    bool act = (t < 24);

    float acc = 0.f;
    float ptv = act ? ptgt[(size_t)nd * 24 + t] : 0.f;
    float dv  = act ? (den[nd * 8 + h] + 1e-9f) : 1.f;
    float inv = 1.f / dv;

    for (int i = 0; i < num; ++i) {
        int p = beg + i;
        int e = cd_e[p];
        int src = cd_src[p];
        float ex  = act ? exb[(size_t)p * 8 + h] : 0.f;
        float ejv = act ? ejb[(size_t)p * 8 + h] : 0.f;
        float psv = act ? psrc[(size_t)src * 48 + r * 24 + t] : 0.f;
        float al = ex * inv;
        float w0c = wig[(size_t)e * 256 + 1 + c];
        acc += al * (psv + ptv) + w0c * (al * ejv);
    }
    acc += __shfl_xor(acc, 1);
    acc += __shfl_xor(acc, 2);
    acc += __shfl_xor(acc, 4);
    if (act && h == 0) out[nd * 3 + c] = acc;
}

// ---------------------------------------------------------------------------
extern "C" void kernel_launch(void* const* d_in, const int* in_sizes, int n_in,
                              void* d_out, int out_size, void* d_ws, size_t ws_size,
                              hipStream_t stream) {
    const float* x    = (const float*)d_in[0];
    const int*   zn   = (const int*)d_in[1];
    const float* dist = (const float*)d_in[2];
    const int*   ei   = (const int*)d_in[3];
    const int*   mask = (const int*)d_in[4];
    const float* wig  = (const float*)d_in[5];
    // per role: emb_s, emb_t, w_d, We, Ws, Wt, Wa, va, Wv, Wo
    const float* fs[10]; const float* dn[10];
    for (int i = 0; i < 10; ++i) { fs[i] = (const float*)d_in[6 + i]; dn[i] = (const float*)d_in[16 + i]; }

    int N = in_sizes[1];   // atomic_numbers count
    int E = in_sizes[2];   // edge_distance count

    // workspace carve-up
    float* cmp  = (float*)d_ws;                    // 2*RS
    float* den  = cmp + 2 * RS;                    // N*8
    float* exb  = den + (size_t)N * 8;             // E*8
    float* ejb  = exb + (size_t)E * 8;             // E*8
    float* psrc = ejb + (size_t)E * 8;             // N*48
    float* ptgt = psrc + (size_t)N * 48;           // N*24
    int* cnt_s  = (int*)(ptgt + (size_t)N * 24);   // N
    int* cnt_d  = cnt_s + N;                       // N
    int* base_s = cnt_d + N;                       // N
    int* base_d = base_s + N;                      // N
    int* woff_s = base_d + N;                      // N
    int* woff_d = woff_s + N;                      // N
    int* cs_e   = woff_d + N;                      // E
    int* cs_src = cs_e + E;                        // E
    int* cs_dst = cs_src + E;                      // E
    int* cd_e   = cs_dst + E;                      // E
    int* cd_src = cd_e + E;                        // E
    int* cd_dst = cd_src + E;                      // E
    int* pos_d  = cd_dst + E;                      // E
    size_t off = (size_t)((char*)(pos_d + E) - (char*)d_ws);
    off = (off + 15) & ~(size_t)15;
    ushort_t* srcA = (ushort_t*)((char*)d_ws + off);      // N*2048 bf16
    ushort_t* tgtA = srcA + (size_t)N * 2048;             // N*1024 bf16
    ushort_t* f0s  = tgtA + (size_t)N * 1024;             // E*64 bf16 (pos-indexed)
    // total ~39.4 MB

    hipMemsetAsync(cnt_s, 0, (size_t)2 * N * sizeof(int), stream);
    hipMemsetAsync(den, 0, (size_t)N * 8 * sizeof(float), stream);

    k_composites<<<dim3(6, 2), 256, 0, stream>>>(
        fs[4], fs[5], fs[3], fs[6], fs[8], fs[9],
        dn[4], dn[5], dn[3], dn[6], dn[8], dn[9], cmp);

    int nodeBlocks = 512;
    int totWaves = nodeBlocks * (256 / 64);
    k_node<<<nodeBlocks, 256, 0, stream>>>(x, mask, cmp, psrc, ptgt, srcA, tgtA, N, totWaves);

    k_hist<<<(E + 255) / 256, 256, 0, stream>>>(ei, cnt_s, cnt_d, E);
    k_scan<<<1, 256, 0, stream>>>(cnt_s, cnt_d, base_s, base_d, woff_s, woff_d, N);
    k_fill<<<(E + 255) / 256, 256, 0, stream>>>(
        ei, woff_s, woff_d, cs_e, cs_src, cs_dst, cd_e, cd_src, cd_dst, pos_d, E);

    int eb = (E + 15) / 16;
    k_srcE<<<eb, 256, 0, stream>>>(cs_e, cs_src, cs_dst, mask, pos_d, wig, srcA, f0s, E);

    k_edge<<<eb, 256, 0, stream>>>(
        cd_e, cd_src, cd_dst, dist, zn, mask, wig, cmp,
        fs[0], fs[1], fs[2], dn[0], dn[1], dn[2],
        fs[7], dn[7], tgtA, f0s, den, exb, ejb, E);

    k_out<<<(N + 3) / 4, 256, 0, stream>>>(
        cd_e, cd_src, mask, wig, psrc, ptgt, exb, ejb, den, base_d, cnt_d,
        (float*)d_out, N);
}